// Round 1
// baseline (482.689 us; speedup 1.0000x reference)
//
#include <hip/hip_runtime.h>
#include <hip/hip_bf16.h>
#include <math.h>

// Shapes (fixed by the problem)
#define BB   512
#define NN   64
#define NFG  1024
#define NFR  256
#define MM   (BB * NN)          // 32768
#define RG_OFF 33554432L        // out elements before relation_graph

typedef __attribute__((ext_vector_type(8))) short bf16x8;   // 8 bf16 = 4 VGPRs (guide §3)
typedef __attribute__((ext_vector_type(4))) float f32x4;
typedef __attribute__((ext_vector_type(8))) unsigned short u16x8;

__device__ inline unsigned short f2bf(float f) {
    union { float f; unsigned u; } v; v.f = f;
    unsigned u = v.u;
    return (unsigned short)((u + 0x7FFFu + ((u >> 16) & 1u)) >> 16);  // RNE
}

__device__ inline void gld_lds16(const unsigned short* g, unsigned short* l) {
    // async global->LDS, 16B per lane; LDS dst is wave-uniform base + lane*16
    __builtin_amdgcn_global_load_lds((const __attribute__((address_space(1))) void*)g,
                                     (__attribute__((address_space(3))) void*)l, 16, 0, 0);
}

// ---------------- converts ----------------

__global__ __launch_bounds__(256) void cast_f32_bf16(const float* __restrict__ in,
                                                     unsigned short* __restrict__ out, long n) {
    long i = ((long)blockIdx.x * 256 + threadIdx.x) * 8;
    if (i + 8 <= n) {
        f32x4 a = *(const f32x4*)(in + i);
        f32x4 b = *(const f32x4*)(in + i + 4);
        u16x8 o;
#pragma unroll
        for (int c = 0; c < 4; ++c) { o[c] = f2bf(a[c]); o[4 + c] = f2bf(b[c]); }
        *(u16x8*)(out + i) = o;
    }
}

// in: [K][N] f32 row-major  ->  out: [N][K] bf16 row-major
__global__ void transpose_cast(const float* __restrict__ in, unsigned short* __restrict__ out,
                               int K, int N) {
    __shared__ float tile[32][33];
    int tx = threadIdx.x, ty = threadIdx.y;
    int k0 = blockIdx.y * 32, n0 = blockIdx.x * 32;
#pragma unroll
    for (int r = 0; r < 4; ++r)
        tile[ty + r * 8][tx] = in[(long)(k0 + ty + r * 8) * N + n0 + tx];
    __syncthreads();
#pragma unroll
    for (int r = 0; r < 4; ++r)
        out[(long)(n0 + ty + r * 8) * K + k0 + tx] = f2bf(tile[tx][ty + r * 8]);
}

__global__ void concat_bias(const float* __restrict__ bt, const float* __restrict__ bp,
                            float* __restrict__ out) {
    int i = threadIdx.x;
    out[i] = (i < 256) ? bt[i] : bp[i - 256];
}

// ---------------- gemm_bt3: C[M][N] = act(A[M][K] @ Bt[N][K]^T + bias) ----------------
// Pipelined (T3+T4+T5): BM=128, BN=256, BK=64, 8 waves (2x4, wave-tile 64x64),
// 3 LDS buffers (144 KB). While computing K-tile j from buf[j%3], tile j+2's stage
// is issued into buf[(j+2)%3]. Entry sync per tile: s_waitcnt vmcnt(6) (tile j+1's
// 6 loads stay in flight) + raw s_barrier. vmcnt(0) only on the final tile.
// Swizzle: stage fetches global chunk (t&7)^(row&7); reads use slot^(l15&7)
// (same involution as the verified 128^2 kernel).
// SWIZ=2: A-panel shared -> ntile fastest within an XCD's slot range.
// SWIZ=1: B-panel shared -> mtile fastest.

template<int RELU, int STORE_BF16, int SWIZ, int LOG_FAST>
__global__ __launch_bounds__(512, 2)
void gemm_bt3(const unsigned short* __restrict__ A, const unsigned short* __restrict__ Bt,
              const float* __restrict__ bias, void* __restrict__ Cout,
              int M, int N, int K) {
    __shared__ __align__(16) unsigned short As[3 * 128 * 64];   // 48 KB
    __shared__ __align__(16) unsigned short Bs[3 * 256 * 64];   // 96 KB
    const int t    = threadIdx.x;
    const int lane = t & 63;
    const int w    = t >> 6;
    const int l15  = lane & 15;
    const int q    = lane >> 4;

    const int mtiles = M >> 7;           // BM=128
    const int ntiles = N >> 8;           // BN=256
    long mtile, ntile;
    {
        long lin  = blockIdx.x;
        int  xcd  = (int)(lin & 7);
        long slot = lin >> 3;
        if (SWIZ == 2) {
            ntile = slot & ((1 << LOG_FAST) - 1);
            mtile = (long)xcd * (mtiles >> 3) + (slot >> LOG_FAST);
        } else {
            mtile = slot & ((1 << LOG_FAST) - 1);
            ntile = (long)xcd * (ntiles >> 3) + (slot >> LOG_FAST);
        }
    }
    const long tileM = mtile * 128;
    const long tileN = ntile * 256;
    const int wm = (w >> 2) * 64;        // 0 / 64
    const int wn = (w & 3) * 64;         // 0 / 64 / 128 / 192

    f32x4 acc[4][4] = {};

    // staging geometry: one instruction = 512 thr x 16B = 8 KB = 64 rows of 128 B
    const int rS = t >> 3;               // row within a 64-row chunk
    const int cS = (t & 7) ^ (rS & 7);   // pre-swizzled global 16B-chunk
    const unsigned short* gA = A  + (tileM + rS) * (long)K + cS * 8;
    const unsigned short* gB = Bt + (tileN + rS) * (long)K + cS * 8;
    const int NTk = K >> 6;

    auto STAGE = [&](int j) {
        const int  buf = j % 3;
        const long kt  = (long)j * 64;
#pragma unroll
        for (int i = 0; i < 2; ++i)      // A: 128 rows = 2 instr
            gld_lds16(gA + (long)i * 64 * K + kt, As + buf * 8192  + (i * 512 + w * 64) * 8);
#pragma unroll
        for (int i = 0; i < 4; ++i)      // B: 256 rows = 4 instr
            gld_lds16(gB + (long)i * 64 * K + kt, Bs + buf * 16384 + (i * 512 + w * 64) * 8);
    };

    STAGE(0);
    STAGE(1);                            // 12 loads/wave in flight

    for (int j = 0; j < NTk; ++j) {
        const int buf = j % 3;
        // own tile-j loads are the oldest; tile j+1's 6 stay outstanding
        if (j < NTk - 1) asm volatile("s_waitcnt vmcnt(6)" ::: "memory");
        else             asm volatile("s_waitcnt vmcnt(0)" ::: "memory");
        __builtin_amdgcn_s_barrier();    // all waves' tile-j loads landed
        __builtin_amdgcn_sched_barrier(0);
        if (j + 2 < NTk) STAGE(j + 2);   // buf[(j+2)%3] fully consumed (tile j-1)
#pragma unroll
        for (int ks = 0; ks < 2; ++ks) {
            const int slot = (ks * 4 + q) ^ (l15 & 7);
            bf16x8 af[4], bf[4];
#pragma unroll
            for (int mi = 0; mi < 4; ++mi)
                af[mi] = *(const bf16x8*)(As + buf * 8192  + (wm + mi * 16 + l15) * 64 + slot * 8);
#pragma unroll
            for (int ni = 0; ni < 4; ++ni)
                bf[ni] = *(const bf16x8*)(Bs + buf * 16384 + (wn + ni * 16 + l15) * 64 + slot * 8);
            __builtin_amdgcn_s_setprio(1);
#pragma unroll
            for (int mi = 0; mi < 4; ++mi)
#pragma unroll
                for (int ni = 0; ni < 4; ++ni)
                    acc[mi][ni] = __builtin_amdgcn_mfma_f32_16x16x32_bf16(af[mi], bf[ni],
                                                                          acc[mi][ni], 0, 0, 0);
            __builtin_amdgcn_s_setprio(0);
        }
    }

    // epilogue: C/D layout col=lane&15, row=(lane>>4)*4+reg (verified m89/m91)
#pragma unroll
    for (int mi = 0; mi < 4; ++mi) {
#pragma unroll
        for (int ni = 0; ni < 4; ++ni) {
            long row0 = tileM + wm + mi * 16 + q * 4;
            long col  = tileN + wn + ni * 16 + l15;
            float bv = bias ? bias[col] : 0.f;
#pragma unroll
            for (int r = 0; r < 4; ++r) {
                float v = acc[mi][ni][r] + bv;
                if (RELU) v = fmaxf(v, 0.f);
                long idx = (row0 + r) * N + col;
                if (STORE_BF16) ((unsigned short*)Cout)[idx] = f2bf(v);
                else            ((float*)Cout)[idx] = v;
            }
        }
    }
}

// ---------------- fused: sim -> mask -> softmax -> rg + out = relu(P @ H) ----------------
// one block (256 thr, 4 waves) per batch element; H stored transposed: HtT[g][i], i=b*64+j

__global__ __launch_bounds__(256)
void fused_softmax_out(const unsigned short* __restrict__ thetaphi,  // [32768][512] bf16
                       const float* __restrict__ boxes,              // [512][64][4]
                       const unsigned short* __restrict__ HtT,       // [1024][32768] bf16
                       float* __restrict__ rg_out,                   // relation_graph f32
                       float* __restrict__ out) {                    // [512][64][1024] f32
    __shared__ __align__(16) float sim_s[64][68];
    __shared__ __align__(16) unsigned short Pb[64][72];   // 144B row stride: 16B-aligned
    __shared__ float cxs[64], cys[64];
    const int t    = threadIdx.x;
    const int b    = blockIdx.x;
    const int lane = t & 63;
    const int w    = t >> 6;
    const int l15  = lane & 15;
    const int q    = lane >> 4;

    if (t < 64) {
        float4 bx = *(const float4*)(boxes + ((long)b * 64 + t) * 4);
        cxs[t] = (bx.x + bx.z) * 0.5f;
        cys[t] = (bx.y + bx.w) * 0.5f;
    }

    // sim[i][j] = theta_i . phi_j / 16 ; wave w does rows w*16..w*16+15
    {
        f32x4 acc[4] = {};
        const unsigned short* thA = thetaphi + ((long)b * 64 + w * 16 + l15) * 512 + q * 8;
        const unsigned short* thB = thetaphi + ((long)b * 64 + l15) * 512 + 256 + q * 8;
#pragma unroll
        for (int kt = 0; kt < 256; kt += 32) {
            bf16x8 a = *(const bf16x8*)(thA + kt);
#pragma unroll
            for (int ni = 0; ni < 4; ++ni) {
                bf16x8 bb = *(const bf16x8*)(thB + (long)ni * 16 * 512 + kt);
                acc[ni] = __builtin_amdgcn_mfma_f32_16x16x32_bf16(a, bb, acc[ni], 0, 0, 0);
            }
        }
#pragma unroll
        for (int ni = 0; ni < 4; ++ni)
#pragma unroll
            for (int r = 0; r < 4; ++r)
                sim_s[w * 16 + q * 4 + r][ni * 16 + l15] = acc[ni][r] * 0.0625f;
    }
    __syncthreads();

    // softmax row i, 4 lanes per row each owning 16 cols; emit rg (f32) and P (bf16, A-layout)
    {
        const int i  = t >> 2;
        const int j0 = (t & 3) * 16;
        const float cxi = cxs[i], cyi = cys[i];
        const float thr = (float)(0.2 * 157.0);
        float vals[16];
        float mx = -__builtin_inff();
#pragma unroll
        for (int jj = 0; jj < 16; ++jj) {
            int j = j0 + jj;
            float dx = cxi - cxs[j];
            float dy = cyi - cys[j];
            bool msk = sqrtf(dx * dx + dy * dy) > thr;
            float s = msk ? -__builtin_inff() : sim_s[i][j];
            vals[jj] = s;
            mx = fmaxf(mx, s);
        }
        mx = fmaxf(mx, __shfl_xor(mx, 1, 64));
        mx = fmaxf(mx, __shfl_xor(mx, 2, 64));
        float sum = 0.f;
#pragma unroll
        for (int jj = 0; jj < 16; ++jj) {
            float e = (vals[jj] == -__builtin_inff()) ? 0.f : __expf(vals[jj] - mx);
            vals[jj] = e;
            sum += e;
        }
        sum += __shfl_xor(sum, 1, 64);
        sum += __shfl_xor(sum, 2, 64);
        float inv = 1.f / sum;   // self always unmasked -> sum > 0
#pragma unroll
        for (int jj = 0; jj < 16; ++jj) {
            int j = j0 + jj;
            float p = vals[jj] * inv;
            rg_out[((long)b * 64 + i) * 64 + j] = p;
            Pb[i][j] = f2bf(p);
        }
    }
    __syncthreads();

    // out[i][g] = relu( sum_j P[i][j] * H[j][g] ), K=64; B-frags from HtT[g][b*64+j]
    {
        const unsigned short* HtB = HtT + (long)b * 64;     // column offset
        float* outB = out + (long)b * 65536;                // [64][1024]
        bf16x8 af[4][2];
#pragma unroll
        for (int mi = 0; mi < 4; ++mi)
#pragma unroll
            for (int kk = 0; kk < 2; ++kk)
                af[mi][kk] = *(const bf16x8*)(&Pb[mi * 16 + l15][kk * 32 + q * 8]);
#pragma unroll 2
        for (int nt = 0; nt < 16; ++nt) {
            const int g0 = w * 256 + nt * 16;
            const unsigned short* hp = HtB + (long)(g0 + l15) * 32768 + q * 8;
            bf16x8 b0 = *(const bf16x8*)(hp);        // j = q*8..q*8+7
            bf16x8 b1 = *(const bf16x8*)(hp + 32);   // j = 32+q*8..
#pragma unroll
            for (int mi = 0; mi < 4; ++mi) {
                f32x4 acc = {};
                acc = __builtin_amdgcn_mfma_f32_16x16x32_bf16(af[mi][0], b0, acc, 0, 0, 0);
                acc = __builtin_amdgcn_mfma_f32_16x16x32_bf16(af[mi][1], b1, acc, 0, 0, 0);
#pragma unroll
                for (int r = 0; r < 4; ++r)
                    outB[(long)(mi * 16 + q * 4 + r) * 1024 + g0 + l15] = fmaxf(acc[r], 0.f);
            }
        }
    }
}

// ---------------- launch ----------------

extern "C" void kernel_launch(void* const* d_in, const int* in_sizes, int n_in,
                              void* d_out, int out_size, void* d_ws, size_t ws_size,
                              hipStream_t stream) {
    const float* feats   = (const float*)d_in[0];
    const float* boxes   = (const float*)d_in[1];
    const float* W_theta = (const float*)d_in[2];
    const float* b_theta = (const float*)d_in[3];
    const float* W_phi   = (const float*)d_in[4];
    const float* b_phi   = (const float*)d_in[5];
    const float* W_gcn   = (const float*)d_in[6];
    float* out = (float*)d_out;

    // workspace layout (~171 MB)
    char* ws = (char*)d_ws;
    unsigned short* featsb   = (unsigned short*)(ws);                // 67108864 B
    unsigned short* thetaphi = (unsigned short*)(ws + 67108864);     // 33554432 B
    unsigned short* HtT      = (unsigned short*)(ws + 100663296);    // 67108864 B
    unsigned short* Wtp      = (unsigned short*)(ws + 167772160);    //  1048576 B
    unsigned short* Wgt      = (unsigned short*)(ws + 168820736);    //  2097152 B
    float*          bias512  = (float*)(ws + 170917888);             //     2048 B

    cast_f32_bf16<<<16384, 256, 0, stream>>>(feats, featsb, 33554432L);
    transpose_cast<<<dim3(8, 32),  dim3(32, 8), 0, stream>>>(W_theta, Wtp,              1024, 256);
    transpose_cast<<<dim3(8, 32),  dim3(32, 8), 0, stream>>>(W_phi,   Wtp + 256 * 1024, 1024, 256);
    transpose_cast<<<dim3(32, 32), dim3(32, 8), 0, stream>>>(W_gcn,   Wgt,              1024, 1024);
    concat_bias<<<1, 512, 0, stream>>>(b_theta, b_phi, bias512);

    // theta|phi: [32768][512] bf16. A=featsb shared by 2 ntiles -> SWIZ=2, 512 blocks
    gemm_bt3<0, 1, 2, 1><<<512, 512, 0, stream>>>(featsb, Wtp, bias512, thetaphi,
                                                  MM, 512, 1024);
    // H^T = Wgcn^T @ feats^T : [1024][32768] bf16. B=featsb shared by 8 mtiles -> SWIZ=1
    gemm_bt3<0, 1, 1, 3><<<1024, 512, 0, stream>>>(Wgt, featsb, nullptr, HtT,
                                                   1024, MM, 1024);
    // relation graph + out = relu(P @ H)
    fused_softmax_out<<<BB, 256, 0, stream>>>(thetaphi, boxes, HtT, out + RG_OFF, out);
}

// Round 2
// 435.334 us; speedup vs baseline: 1.1088x; 1.1088x over previous
//
#include <hip/hip_runtime.h>
#include <hip/hip_bf16.h>
#include <math.h>

// Shapes (fixed by the problem)
#define BB   512
#define NN   64
#define NFG  1024
#define NFR  256
#define MM   (BB * NN)          // 32768
#define RG_OFF 33554432L        // out elements before relation_graph

typedef __attribute__((ext_vector_type(8))) short bf16x8;   // 8 bf16 = 4 VGPRs (guide §3)
typedef __attribute__((ext_vector_type(4))) float f32x4;
typedef __attribute__((ext_vector_type(8))) unsigned short u16x8;

__device__ inline unsigned short f2bf(float f) {
    union { float f; unsigned u; } v; v.f = f;
    unsigned u = v.u;
    return (unsigned short)((u + 0x7FFFu + ((u >> 16) & 1u)) >> 16);  // RNE
}

__device__ inline void gld_lds16(const unsigned short* g, unsigned short* l) {
    // async global->LDS, 16B per lane; LDS dst is wave-uniform base + lane*16
    __builtin_amdgcn_global_load_lds((const __attribute__((address_space(1))) void*)g,
                                     (__attribute__((address_space(3))) void*)l, 16, 0, 0);
}

// ---------------- prep: cast + 3 weight transposes + bias concat, one launch ----------------
// block roles by blockIdx.x: [0,16384) cast feats; [16384,16640) W_theta^T;
// [16640,16896) W_phi^T; [16896,17920) W_gcn^T; [17920] bias concat.

__device__ void tcast_body(const float* __restrict__ in, unsigned short* __restrict__ out,
                           int K, int N, int bx, int by, float tile[32][33]) {
    const int t  = threadIdx.x;
    const int tx = t & 31, ty = t >> 5;
    const int k0 = by * 32, n0 = bx * 32;
#pragma unroll
    for (int r = 0; r < 4; ++r)
        tile[ty + r * 8][tx] = in[(long)(k0 + ty + r * 8) * N + n0 + tx];
    __syncthreads();
#pragma unroll
    for (int r = 0; r < 4; ++r)
        out[(long)(n0 + ty + r * 8) * K + k0 + tx] = f2bf(tile[tx][ty + r * 8]);
}

__global__ __launch_bounds__(256)
void prep(const float* __restrict__ feats, unsigned short* __restrict__ featsb,
          const float* __restrict__ W_theta, const float* __restrict__ W_phi,
          const float* __restrict__ W_gcn,
          unsigned short* __restrict__ Wtp, unsigned short* __restrict__ Wgt,
          const float* __restrict__ bt, const float* __restrict__ bp,
          float* __restrict__ bias512) {
    __shared__ float tile[32][33];
    const int bid = blockIdx.x;
    const int t   = threadIdx.x;
    if (bid < 16384) {
        long i = ((long)bid * 256 + t) * 8;
        if (i + 8 <= 33554432L) {
            f32x4 a = *(const f32x4*)(feats + i);
            f32x4 b = *(const f32x4*)(feats + i + 4);
            u16x8 o;
#pragma unroll
            for (int c = 0; c < 4; ++c) { o[c] = f2bf(a[c]); o[4 + c] = f2bf(b[c]); }
            *(u16x8*)(featsb + i) = o;
        }
    } else if (bid < 16640) {
        int r = bid - 16384;
        tcast_body(W_theta, Wtp, 1024, 256, r & 7, r >> 3, tile);
    } else if (bid < 16896) {
        int r = bid - 16640;
        tcast_body(W_phi, Wtp + 256 * 1024, 1024, 256, r & 7, r >> 3, tile);
    } else if (bid < 17920) {
        int r = bid - 16896;
        tcast_body(W_gcn, Wgt, 1024, 1024, r & 31, r >> 5, tile);
    } else {
        bias512[t]       = bt[t];
        bias512[t + 256] = bp[t];
    }
}

// ---------------- gemm_bt: C[M][N] = act(A[M][K] @ Bt[N][K]^T + bias) ----------------
// 128x128 tile, 4 waves 2x2, each wave 64x64 (4x4 mfma 16x16x32 acc), BK=64.
// Verified m97-class structure: 32 KB LDS -> 4 blocks/CU, inter-block overlap (m114)
// is what hides the per-tile vmcnt(0)+barrier drain.
// SWIZ: 1 = B-operand reused (mtile fastest, LOG_FAST=log2(gridDim.x));
//       2 = A-operand reused (ntile fastest, LOG_FAST=log2(gridDim.y)).

template<int RELU, int STORE_BF16, int SWIZ, int LOG_FAST>
__global__ __launch_bounds__(256, 4)
void gemm_bt(const unsigned short* __restrict__ A, const unsigned short* __restrict__ Bt,
             const float* __restrict__ bias, void* __restrict__ Cout,
             int M, int N, int K) {
    __shared__ __align__(16) unsigned short As[128 * 64];   // 16 KB
    __shared__ __align__(16) unsigned short Bs[128 * 64];   // 16 KB
    const int t    = threadIdx.x;
    const int lane = t & 63;
    const int w    = t >> 6;
    const int l15  = lane & 15;
    const int q    = lane >> 4;

    long mtile, ntile;
    if (SWIZ == 1) {
        long linear = (long)blockIdx.y * gridDim.x + blockIdx.x;  // dispatch order, x fastest
        int  xcd  = (int)(linear & 7);
        long slot = linear >> 3;
        mtile = slot & ((1 << LOG_FAST) - 1);
        ntile = (long)xcd * (gridDim.y >> 3) + (slot >> LOG_FAST);
    } else if (SWIZ == 2) {
        long linear = (long)blockIdx.y * gridDim.x + blockIdx.x;
        int  xcd  = (int)(linear & 7);
        long slot = linear >> 3;
        ntile = slot & ((1 << LOG_FAST) - 1);
        mtile = (long)xcd * (gridDim.x >> 3) + (slot >> LOG_FAST);
    } else {
        mtile = blockIdx.x; ntile = blockIdx.y;
    }
    const long tileM = mtile * 128;
    const long tileN = ntile * 128;
    const int wm = (w & 1) * 64;
    const int wn = (w >> 1) * 64;

    f32x4 acc[4][4] = {};

    // staging: 4 issues per operand. issue i, thread t -> LDS chunkid = i*256+t
    //   -> LDS row = i*32 + (t>>3), LDS slot = t&7.
    // lane fetches GLOBAL chunk (t&7)^(row&7) so slot s of row r holds chunk s^(r&7).
    const int rS = t >> 3;                 // 0..31
    const int cS = (t & 7) ^ (rS & 7);     // swizzled global chunk
    const unsigned short* gA = A  + (tileM + rS) * (long)K + cS * 8;
    const unsigned short* gB = Bt + (tileN + rS) * (long)K + cS * 8;

    for (int kt = 0; kt < K; kt += 64) {
        __syncthreads();                 // protect LDS reuse
#pragma unroll
        for (int i = 0; i < 4; ++i) {
            gld_lds16(gA + (long)i * 32 * K + kt, As + (i * 256 + w * 64) * 8);
            gld_lds16(gB + (long)i * 32 * K + kt, Bs + (i * 256 + w * 64) * 8);
        }
        __syncthreads();                 // drain staging (compiler emits vmcnt(0))
#pragma unroll
        for (int ks = 0; ks < 2; ++ks) {
            const int slot = (ks * 4 + q) ^ (l15 & 7);   // row&7 == l15&7 (16|wm,mi*16)
            bf16x8 af[4], bf[4];
#pragma unroll
            for (int mi = 0; mi < 4; ++mi)
                af[mi] = *(const bf16x8*)(As + (wm + mi * 16 + l15) * 64 + slot * 8);
#pragma unroll
            for (int ni = 0; ni < 4; ++ni)
                bf[ni] = *(const bf16x8*)(Bs + (wn + ni * 16 + l15) * 64 + slot * 8);
#pragma unroll
            for (int mi = 0; mi < 4; ++mi)
#pragma unroll
                for (int ni = 0; ni < 4; ++ni)
                    acc[mi][ni] = __builtin_amdgcn_mfma_f32_16x16x32_bf16(af[mi], bf[ni],
                                                                          acc[mi][ni], 0, 0, 0);
        }
    }

    // epilogue: C/D layout col=lane&15, row=(lane>>4)*4+reg (verified m89/m91)
#pragma unroll
    for (int mi = 0; mi < 4; ++mi) {
#pragma unroll
        for (int ni = 0; ni < 4; ++ni) {
            long row0 = tileM + wm + mi * 16 + q * 4;
            long col  = tileN + wn + ni * 16 + l15;
            float bv = bias ? bias[col] : 0.f;
#pragma unroll
            for (int r = 0; r < 4; ++r) {
                float v = acc[mi][ni][r] + bv;
                if (RELU) v = fmaxf(v, 0.f);
                long idx = (row0 + r) * N + col;
                if (STORE_BF16) ((unsigned short*)Cout)[idx] = f2bf(v);
                else            ((float*)Cout)[idx] = v;
            }
        }
    }
}

// ---------------- fused: sim -> mask -> softmax -> rg + out = relu(P @ H) ----------------
// 2 blocks per batch element (g-split): block = (b, gh); each computes full sim/softmax
// (cheap, L2-absorbed re-read) but only half the PV g-range -> 4 blocks/CU of TLP for
// the latency-bound strided HtT loads + out stores. rg written by gh==0 only.

__global__ __launch_bounds__(256)
void fused_softmax_out(const unsigned short* __restrict__ thetaphi,  // [32768][512] bf16
                       const float* __restrict__ boxes,              // [512][64][4]
                       const unsigned short* __restrict__ HtT,       // [1024][32768] bf16
                       float* __restrict__ rg_out,                   // relation_graph f32
                       float* __restrict__ out) {                    // [512][64][1024] f32
    __shared__ __align__(16) float sim_s[64][68];
    __shared__ __align__(16) unsigned short Pb[64][72];   // 144B row stride: 16B-aligned
    __shared__ float cxs[64], cys[64];
    const int t    = threadIdx.x;
    const int b    = blockIdx.x >> 1;
    const int gh   = blockIdx.x & 1;
    const int lane = t & 63;
    const int w    = t >> 6;
    const int l15  = lane & 15;
    const int q    = lane >> 4;

    if (t < 64) {
        float4 bx = *(const float4*)(boxes + ((long)b * 64 + t) * 4);
        cxs[t] = (bx.x + bx.z) * 0.5f;
        cys[t] = (bx.y + bx.w) * 0.5f;
    }

    // sim[i][j] = theta_i . phi_j / 16 ; wave w does rows w*16..w*16+15
    {
        f32x4 acc[4] = {};
        const unsigned short* thA = thetaphi + ((long)b * 64 + w * 16 + l15) * 512 + q * 8;
        const unsigned short* thB = thetaphi + ((long)b * 64 + l15) * 512 + 256 + q * 8;
#pragma unroll
        for (int kt = 0; kt < 256; kt += 32) {
            bf16x8 a = *(const bf16x8*)(thA + kt);
#pragma unroll
            for (int ni = 0; ni < 4; ++ni) {
                bf16x8 bb = *(const bf16x8*)(thB + (long)ni * 16 * 512 + kt);
                acc[ni] = __builtin_amdgcn_mfma_f32_16x16x32_bf16(a, bb, acc[ni], 0, 0, 0);
            }
        }
#pragma unroll
        for (int ni = 0; ni < 4; ++ni)
#pragma unroll
            for (int r = 0; r < 4; ++r)
                sim_s[w * 16 + q * 4 + r][ni * 16 + l15] = acc[ni][r] * 0.0625f;
    }
    __syncthreads();

    // softmax row i, 4 lanes per row each owning 16 cols; emit rg (f32) and P (bf16, A-layout)
    {
        const int i  = t >> 2;
        const int j0 = (t & 3) * 16;
        const float cxi = cxs[i], cyi = cys[i];
        const float thr = (float)(0.2 * 157.0);
        float vals[16];
        float mx = -__builtin_inff();
#pragma unroll
        for (int jj = 0; jj < 16; ++jj) {
            int j = j0 + jj;
            float dx = cxi - cxs[j];
            float dy = cyi - cys[j];
            bool msk = sqrtf(dx * dx + dy * dy) > thr;
            float s = msk ? -__builtin_inff() : sim_s[i][j];
            vals[jj] = s;
            mx = fmaxf(mx, s);
        }
        mx = fmaxf(mx, __shfl_xor(mx, 1, 64));
        mx = fmaxf(mx, __shfl_xor(mx, 2, 64));
        float sum = 0.f;
#pragma unroll
        for (int jj = 0; jj < 16; ++jj) {
            float e = (vals[jj] == -__builtin_inff()) ? 0.f : __expf(vals[jj] - mx);
            vals[jj] = e;
            sum += e;
        }
        sum += __shfl_xor(sum, 1, 64);
        sum += __shfl_xor(sum, 2, 64);
        float inv = 1.f / sum;   // self always unmasked -> sum > 0
#pragma unroll
        for (int jj = 0; jj < 16; ++jj) {
            int j = j0 + jj;
            float p = vals[jj] * inv;
            if (gh == 0) rg_out[((long)b * 64 + i) * 64 + j] = p;
            Pb[i][j] = f2bf(p);
        }
    }
    __syncthreads();

    // out[i][g] = relu( sum_j P[i][j] * H[j][g] ), K=64; B-frags from HtT[g][b*64+j]
    // this block covers g in [gh*512, gh*512+512): wave w owns 128 g's.
    {
        const unsigned short* HtB = HtT + (long)b * 64;     // column offset
        float* outB = out + (long)b * 65536;                // [64][1024]
        bf16x8 af[4][2];
#pragma unroll
        for (int mi = 0; mi < 4; ++mi)
#pragma unroll
            for (int kk = 0; kk < 2; ++kk)
                af[mi][kk] = *(const bf16x8*)(&Pb[mi * 16 + l15][kk * 32 + q * 8]);
#pragma unroll 2
        for (int nt = 0; nt < 8; ++nt) {
            const int g0 = gh * 512 + w * 128 + nt * 16;
            const unsigned short* hp = HtB + (long)(g0 + l15) * 32768 + q * 8;
            bf16x8 b0 = *(const bf16x8*)(hp);        // j = q*8..q*8+7
            bf16x8 b1 = *(const bf16x8*)(hp + 32);   // j = 32+q*8..
#pragma unroll
            for (int mi = 0; mi < 4; ++mi) {
                f32x4 acc = {};
                acc = __builtin_amdgcn_mfma_f32_16x16x32_bf16(af[mi][0], b0, acc, 0, 0, 0);
                acc = __builtin_amdgcn_mfma_f32_16x16x32_bf16(af[mi][1], b1, acc, 0, 0, 0);
#pragma unroll
                for (int r = 0; r < 4; ++r)
                    outB[(long)(mi * 16 + q * 4 + r) * 1024 + g0 + l15] = fmaxf(acc[r], 0.f);
            }
        }
    }
}

// ---------------- launch ----------------

extern "C" void kernel_launch(void* const* d_in, const int* in_sizes, int n_in,
                              void* d_out, int out_size, void* d_ws, size_t ws_size,
                              hipStream_t stream) {
    const float* feats   = (const float*)d_in[0];
    const float* boxes   = (const float*)d_in[1];
    const float* W_theta = (const float*)d_in[2];
    const float* b_theta = (const float*)d_in[3];
    const float* W_phi   = (const float*)d_in[4];
    const float* b_phi   = (const float*)d_in[5];
    const float* W_gcn   = (const float*)d_in[6];
    float* out = (float*)d_out;

    // workspace layout (~171 MB)
    char* ws = (char*)d_ws;
    unsigned short* featsb   = (unsigned short*)(ws);                // 67108864 B
    unsigned short* thetaphi = (unsigned short*)(ws + 67108864);     // 33554432 B
    unsigned short* HtT      = (unsigned short*)(ws + 100663296);    // 67108864 B
    unsigned short* Wtp      = (unsigned short*)(ws + 167772160);    //  1048576 B
    unsigned short* Wgt      = (unsigned short*)(ws + 168820736);    //  2097152 B
    float*          bias512  = (float*)(ws + 170917888);             //     2048 B

    // cast + weight transposes + bias, one launch
    prep<<<17921, 256, 0, stream>>>(feats, featsb, W_theta, W_phi, W_gcn,
                                    Wtp, Wgt, b_theta, b_phi, bias512);

    // theta|phi: [32768][512] bf16 row-major. A=featsb reused by 4 ntiles -> SWIZ=2
    gemm_bt<0, 1, 2, 2><<<dim3(256, 4), 256, 0, stream>>>(featsb, Wtp, bias512, thetaphi,
                                                          MM, 512, 1024);
    // H^T = Wgcn^T @ feats^T : [1024][32768] bf16. B=featsb reused by 8 mtiles -> SWIZ=1
    gemm_bt<0, 1, 1, 3><<<dim3(8, 256), 256, 0, stream>>>(Wgt, featsb, nullptr, HtT,
                                                          1024, MM, 1024);
    // relation graph + out = relu(P @ H), g-split x2
    fused_softmax_out<<<BB * 2, 256, 0, stream>>>(thetaphi, boxes, HtT, out + RG_OFF, out);
}

// Round 3
// 417.923 us; speedup vs baseline: 1.1550x; 1.0417x over previous
//
#include <hip/hip_runtime.h>
#include <hip/hip_bf16.h>
#include <math.h>

// Shapes (fixed by the problem)
#define BB   512
#define NN   64
#define NFG  1024
#define NFR  256
#define MM   (BB * NN)          // 32768
#define RG_OFF 33554432L        // out elements before relation_graph

typedef __attribute__((ext_vector_type(8))) short bf16x8;   // 8 bf16 = 4 VGPRs (guide §3)
typedef __attribute__((ext_vector_type(4))) float f32x4;
typedef __attribute__((ext_vector_type(8))) unsigned short u16x8;

__device__ inline unsigned short f2bf(float f) {
    union { float f; unsigned u; } v; v.f = f;
    unsigned u = v.u;
    return (unsigned short)((u + 0x7FFFu + ((u >> 16) & 1u)) >> 16);  // RNE
}

__device__ inline void gld_lds16(const unsigned short* g, unsigned short* l) {
    // async global->LDS, 16B per lane; LDS dst is wave-uniform base + lane*16
    __builtin_amdgcn_global_load_lds((const __attribute__((address_space(1))) void*)g,
                                     (__attribute__((address_space(3))) void*)l, 16, 0, 0);
}

// ---------------- prep: cast + 3 weight transposes + bias concat, one launch ----------------
// block roles by blockIdx.x: [0,16384) cast feats; [16384,16640) W_theta^T;
// [16640,16896) W_phi^T; [16896,17920) W_gcn^T; [17920] bias concat.

__device__ void tcast_body(const float* __restrict__ in, unsigned short* __restrict__ out,
                           int K, int N, int bx, int by, float tile[32][33]) {
    const int t  = threadIdx.x;
    const int tx = t & 31, ty = t >> 5;
    const int k0 = by * 32, n0 = bx * 32;
#pragma unroll
    for (int r = 0; r < 4; ++r)
        tile[ty + r * 8][tx] = in[(long)(k0 + ty + r * 8) * N + n0 + tx];
    __syncthreads();
#pragma unroll
    for (int r = 0; r < 4; ++r)
        out[(long)(n0 + ty + r * 8) * K + k0 + tx] = f2bf(tile[tx][ty + r * 8]);
}

__global__ __launch_bounds__(256)
void prep(const float* __restrict__ feats, unsigned short* __restrict__ featsb,
          const float* __restrict__ W_theta, const float* __restrict__ W_phi,
          const float* __restrict__ W_gcn,
          unsigned short* __restrict__ Wtp, unsigned short* __restrict__ Wgt,
          const float* __restrict__ bt, const float* __restrict__ bp,
          float* __restrict__ bias512) {
    __shared__ float tile[32][33];
    const int bid = blockIdx.x;
    const int t   = threadIdx.x;
    if (bid < 16384) {
        long i = ((long)bid * 256 + t) * 8;
        if (i + 8 <= 33554432L) {
            f32x4 a = *(const f32x4*)(feats + i);
            f32x4 b = *(const f32x4*)(feats + i + 4);
            u16x8 o;
#pragma unroll
            for (int c = 0; c < 4; ++c) { o[c] = f2bf(a[c]); o[4 + c] = f2bf(b[c]); }
            *(u16x8*)(featsb + i) = o;
        }
    } else if (bid < 16640) {
        int r = bid - 16384;
        tcast_body(W_theta, Wtp, 1024, 256, r & 7, r >> 3, tile);
    } else if (bid < 16896) {
        int r = bid - 16640;
        tcast_body(W_phi, Wtp + 256 * 1024, 1024, 256, r & 7, r >> 3, tile);
    } else if (bid < 17920) {
        int r = bid - 16896;
        tcast_body(W_gcn, Wgt, 1024, 1024, r & 31, r >> 5, tile);
    } else {
        bias512[t]       = bt[t];
        bias512[t + 256] = bp[t];
    }
}

// ---------------- gemm_bt: C[M][N] = act(A[M][K] @ Bt[N][K]^T + bias) ----------------
// 128x128 tile, 4 waves 2x2, each wave 64x64 (4x4 mfma 16x16x32 acc), BK=64.
// Verified m97-class structure: 32 KB LDS -> 4 blocks/CU, inter-block overlap (m114)
// is what hides the per-tile vmcnt(0)+barrier drain.
// SWIZ: 1 = B-operand reused (mtile fastest, LOG_FAST=log2(gridDim.x));
//       2 = A-operand reused (ntile fastest, LOG_FAST=log2(gridDim.y)).

template<int RELU, int STORE_BF16, int SWIZ, int LOG_FAST>
__global__ __launch_bounds__(256, 4)
void gemm_bt(const unsigned short* __restrict__ A, const unsigned short* __restrict__ Bt,
             const float* __restrict__ bias, void* __restrict__ Cout,
             int M, int N, int K) {
    __shared__ __align__(16) unsigned short As[128 * 64];   // 16 KB
    __shared__ __align__(16) unsigned short Bs[128 * 64];   // 16 KB
    const int t    = threadIdx.x;
    const int lane = t & 63;
    const int w    = t >> 6;
    const int l15  = lane & 15;
    const int q    = lane >> 4;

    long mtile, ntile;
    if (SWIZ == 1) {
        long linear = (long)blockIdx.y * gridDim.x + blockIdx.x;  // dispatch order, x fastest
        int  xcd  = (int)(linear & 7);
        long slot = linear >> 3;
        mtile = slot & ((1 << LOG_FAST) - 1);
        ntile = (long)xcd * (gridDim.y >> 3) + (slot >> LOG_FAST);
    } else if (SWIZ == 2) {
        long linear = (long)blockIdx.y * gridDim.x + blockIdx.x;
        int  xcd  = (int)(linear & 7);
        long slot = linear >> 3;
        ntile = slot & ((1 << LOG_FAST) - 1);
        mtile = (long)xcd * (gridDim.x >> 3) + (slot >> LOG_FAST);
    } else {
        mtile = blockIdx.x; ntile = blockIdx.y;
    }
    const long tileM = mtile * 128;
    const long tileN = ntile * 128;
    const int wm = (w & 1) * 64;
    const int wn = (w >> 1) * 64;

    f32x4 acc[4][4] = {};

    // staging: 4 issues per operand. issue i, thread t -> LDS chunkid = i*256+t
    //   -> LDS row = i*32 + (t>>3), LDS slot = t&7.
    // lane fetches GLOBAL chunk (t&7)^(row&7) so slot s of row r holds chunk s^(r&7).
    const int rS = t >> 3;                 // 0..31
    const int cS = (t & 7) ^ (rS & 7);     // swizzled global chunk
    const unsigned short* gA = A  + (tileM + rS) * (long)K + cS * 8;
    const unsigned short* gB = Bt + (tileN + rS) * (long)K + cS * 8;

    for (int kt = 0; kt < K; kt += 64) {
        __syncthreads();                 // protect LDS reuse
#pragma unroll
        for (int i = 0; i < 4; ++i) {
            gld_lds16(gA + (long)i * 32 * K + kt, As + (i * 256 + w * 64) * 8);
            gld_lds16(gB + (long)i * 32 * K + kt, Bs + (i * 256 + w * 64) * 8);
        }
        __syncthreads();                 // drain staging (compiler emits vmcnt(0))
#pragma unroll
        for (int ks = 0; ks < 2; ++ks) {
            const int slot = (ks * 4 + q) ^ (l15 & 7);   // row&7 == l15&7 (16|wm,mi*16)
            bf16x8 af[4], bf[4];
#pragma unroll
            for (int mi = 0; mi < 4; ++mi)
                af[mi] = *(const bf16x8*)(As + (wm + mi * 16 + l15) * 64 + slot * 8);
#pragma unroll
            for (int ni = 0; ni < 4; ++ni)
                bf[ni] = *(const bf16x8*)(Bs + (wn + ni * 16 + l15) * 64 + slot * 8);
#pragma unroll
            for (int mi = 0; mi < 4; ++mi)
#pragma unroll
                for (int ni = 0; ni < 4; ++ni)
                    acc[mi][ni] = __builtin_amdgcn_mfma_f32_16x16x32_bf16(af[mi], bf[ni],
                                                                          acc[mi][ni], 0, 0, 0);
        }
    }

    // epilogue: C/D layout col=lane&15, row=(lane>>4)*4+reg (verified m89/m91)
#pragma unroll
    for (int mi = 0; mi < 4; ++mi) {
#pragma unroll
        for (int ni = 0; ni < 4; ++ni) {
            long row0 = tileM + wm + mi * 16 + q * 4;
            long col  = tileN + wn + ni * 16 + l15;
            float bv = bias ? bias[col] : 0.f;
#pragma unroll
            for (int r = 0; r < 4; ++r) {
                float v = acc[mi][ni][r] + bv;
                if (RELU) v = fmaxf(v, 0.f);
                long idx = (row0 + r) * N + col;
                if (STORE_BF16) ((unsigned short*)Cout)[idx] = f2bf(v);
                else            ((float*)Cout)[idx] = v;
            }
        }
    }
}

// ---------------- fused: sim -> mask -> softmax -> rg + out = relu(P @ H) ----------------
// 2 blocks per batch element (g-split): block = (b, gh). The block's entire HtT
// working set (16 bf16x8/wave = 64 VGPRs) is PREFETCHED at kernel entry, pinned by
// sched_barrier(0), so the ~500-900 cy HBM latency hides under sim+softmax (T14:
// there IS a compute phase here, unlike pure streaming ops). rg written by gh==0.

__global__ __launch_bounds__(256)
void fused_softmax_out(const unsigned short* __restrict__ thetaphi,  // [32768][512] bf16
                       const float* __restrict__ boxes,              // [512][64][4]
                       const unsigned short* __restrict__ HtT,       // [1024][32768] bf16
                       float* __restrict__ rg_out,                   // relation_graph f32
                       float* __restrict__ out) {                    // [512][64][1024] f32
    __shared__ __align__(16) float sim_s[64][68];
    __shared__ __align__(16) unsigned short Pb[64][72];   // 144B row stride: 16B-aligned
    __shared__ float cxs[64], cys[64];
    const int t    = threadIdx.x;
    const int b    = blockIdx.x >> 1;
    const int gh   = blockIdx.x & 1;
    const int lane = t & 63;
    const int w    = t >> 6;
    const int l15  = lane & 15;
    const int q    = lane >> 4;

    // ---- prefetch HtT b-fragments for phase 3 (issued before any compute) ----
    const unsigned short* HtB = HtT + (long)b * 64;       // column offset
    bf16x8 hb0[8], hb1[8];
#pragma unroll
    for (int nt = 0; nt < 8; ++nt) {
        const int g0 = gh * 512 + w * 128 + nt * 16;
        const unsigned short* hp = HtB + (long)(g0 + l15) * 32768 + q * 8;
        hb0[nt] = *(const bf16x8*)(hp);        // j = q*8..q*8+7
        hb1[nt] = *(const bf16x8*)(hp + 32);   // j = 32+q*8..
    }
    __builtin_amdgcn_sched_barrier(0);         // pin the loads before the compute phases

    if (t < 64) {
        float4 bx = *(const float4*)(boxes + ((long)b * 64 + t) * 4);
        cxs[t] = (bx.x + bx.z) * 0.5f;
        cys[t] = (bx.y + bx.w) * 0.5f;
    }

    // sim[i][j] = theta_i . phi_j / 16 ; wave w does rows w*16..w*16+15
    {
        f32x4 acc[4] = {};
        const unsigned short* thA = thetaphi + ((long)b * 64 + w * 16 + l15) * 512 + q * 8;
        const unsigned short* thB = thetaphi + ((long)b * 64 + l15) * 512 + 256 + q * 8;
#pragma unroll
        for (int kt = 0; kt < 256; kt += 32) {
            bf16x8 a = *(const bf16x8*)(thA + kt);
#pragma unroll
            for (int ni = 0; ni < 4; ++ni) {
                bf16x8 bb = *(const bf16x8*)(thB + (long)ni * 16 * 512 + kt);
                acc[ni] = __builtin_amdgcn_mfma_f32_16x16x32_bf16(a, bb, acc[ni], 0, 0, 0);
            }
        }
#pragma unroll
        for (int ni = 0; ni < 4; ++ni)
#pragma unroll
            for (int r = 0; r < 4; ++r)
                sim_s[w * 16 + q * 4 + r][ni * 16 + l15] = acc[ni][r] * 0.0625f;
    }
    __syncthreads();

    // softmax row i, 4 lanes per row each owning 16 cols; emit rg (f32) and P (bf16, A-layout)
    {
        const int i  = t >> 2;
        const int j0 = (t & 3) * 16;
        const float cxi = cxs[i], cyi = cys[i];
        const float thr = (float)(0.2 * 157.0);
        float vals[16];
        float mx = -__builtin_inff();
#pragma unroll
        for (int jj = 0; jj < 16; ++jj) {
            int j = j0 + jj;
            float dx = cxi - cxs[j];
            float dy = cyi - cys[j];
            bool msk = sqrtf(dx * dx + dy * dy) > thr;
            float s = msk ? -__builtin_inff() : sim_s[i][j];
            vals[jj] = s;
            mx = fmaxf(mx, s);
        }
        mx = fmaxf(mx, __shfl_xor(mx, 1, 64));
        mx = fmaxf(mx, __shfl_xor(mx, 2, 64));
        float sum = 0.f;
#pragma unroll
        for (int jj = 0; jj < 16; ++jj) {
            float e = (vals[jj] == -__builtin_inff()) ? 0.f : __expf(vals[jj] - mx);
            vals[jj] = e;
            sum += e;
        }
        sum += __shfl_xor(sum, 1, 64);
        sum += __shfl_xor(sum, 2, 64);
        float inv = 1.f / sum;   // self always unmasked -> sum > 0
#pragma unroll
        for (int jj = 0; jj < 16; ++jj) {
            int j = j0 + jj;
            float p = vals[jj] * inv;
            if (gh == 0) rg_out[((long)b * 64 + i) * 64 + j] = p;
            Pb[i][j] = f2bf(p);
        }
    }
    __syncthreads();

    // out[i][g] = relu( sum_j P[i][j] * H[j][g] ), K=64; B-frags already in registers.
    // this block covers g in [gh*512, gh*512+512): wave w owns 128 g's.
    {
        float* outB = out + (long)b * 65536;                // [64][1024]
        bf16x8 af[4][2];
#pragma unroll
        for (int mi = 0; mi < 4; ++mi)
#pragma unroll
            for (int kk = 0; kk < 2; ++kk)
                af[mi][kk] = *(const bf16x8*)(&Pb[mi * 16 + l15][kk * 32 + q * 8]);
#pragma unroll
        for (int nt = 0; nt < 8; ++nt) {
            const int g0 = gh * 512 + w * 128 + nt * 16;
#pragma unroll
            for (int mi = 0; mi < 4; ++mi) {
                f32x4 acc = {};
                acc = __builtin_amdgcn_mfma_f32_16x16x32_bf16(af[mi][0], hb0[nt], acc, 0, 0, 0);
                acc = __builtin_amdgcn_mfma_f32_16x16x32_bf16(af[mi][1], hb1[nt], acc, 0, 0, 0);
#pragma unroll
                for (int r = 0; r < 4; ++r)
                    outB[(long)(mi * 16 + q * 4 + r) * 1024 + g0 + l15] = fmaxf(acc[r], 0.f);
            }
        }
    }
}

// ---------------- launch ----------------

extern "C" void kernel_launch(void* const* d_in, const int* in_sizes, int n_in,
                              void* d_out, int out_size, void* d_ws, size_t ws_size,
                              hipStream_t stream) {
    const float* feats   = (const float*)d_in[0];
    const float* boxes   = (const float*)d_in[1];
    const float* W_theta = (const float*)d_in[2];
    const float* b_theta = (const float*)d_in[3];
    const float* W_phi   = (const float*)d_in[4];
    const float* b_phi   = (const float*)d_in[5];
    const float* W_gcn   = (const float*)d_in[6];
    float* out = (float*)d_out;

    // workspace layout (~171 MB)
    char* ws = (char*)d_ws;
    unsigned short* featsb   = (unsigned short*)(ws);                // 67108864 B
    unsigned short* thetaphi = (unsigned short*)(ws + 67108864);     // 33554432 B
    unsigned short* HtT      = (unsigned short*)(ws + 100663296);    // 67108864 B
    unsigned short* Wtp      = (unsigned short*)(ws + 167772160);    //  1048576 B
    unsigned short* Wgt      = (unsigned short*)(ws + 168820736);    //  2097152 B
    float*          bias512  = (float*)(ws + 170917888);             //     2048 B

    // cast + weight transposes + bias, one launch
    prep<<<17921, 256, 0, stream>>>(feats, featsb, W_theta, W_phi, W_gcn,
                                    Wtp, Wgt, b_theta, b_phi, bias512);

    // theta|phi: [32768][512] bf16 row-major. A=featsb reused by 4 ntiles -> SWIZ=2
    gemm_bt<0, 1, 2, 2><<<dim3(256, 4), 256, 0, stream>>>(featsb, Wtp, bias512, thetaphi,
                                                          MM, 512, 1024);
    // H^T = Wgcn^T @ feats^T : [1024][32768] bf16. B=featsb reused by 8 mtiles -> SWIZ=1
    gemm_bt<0, 1, 1, 3><<<dim3(8, 256), 256, 0, stream>>>(Wgt, featsb, nullptr, HtT,
                                                          1024, MM, 1024);
    // relation graph + out = relu(P @ H), g-split x2, HtT prefetched into registers
    fused_softmax_out<<<BB * 2, 256, 0, stream>>>(thetaphi, boxes, HtT, out + RG_OFF, out);
}

// Round 4
// 416.307 us; speedup vs baseline: 1.1595x; 1.0039x over previous
//
#include <hip/hip_runtime.h>
#include <hip/hip_bf16.h>
#include <math.h>

// Shapes (fixed by the problem)
#define BB   512
#define NN   64
#define NFG  1024
#define NFR  256
#define MM   (BB * NN)          // 32768
#define RG_OFF 33554432L        // out elements before relation_graph

typedef __attribute__((ext_vector_type(8))) short bf16x8;   // 8 bf16 = 4 VGPRs (guide §3)
typedef __attribute__((ext_vector_type(4))) float f32x4;
typedef __attribute__((ext_vector_type(8))) unsigned short u16x8;

__device__ inline unsigned short f2bf(float f) {
    union { float f; unsigned u; } v; v.f = f;
    unsigned u = v.u;
    return (unsigned short)((u + 0x7FFFu + ((u >> 16) & 1u)) >> 16);  // RNE
}

__device__ inline void gld_lds16(const unsigned short* g, unsigned short* l) {
    // async global->LDS, 16B per lane; LDS dst is wave-uniform base + lane*16
    __builtin_amdgcn_global_load_lds((const __attribute__((address_space(1))) void*)g,
                                     (__attribute__((address_space(3))) void*)l, 16, 0, 0);
}

// intra-wave LDS handoff fence: pins compiler ordering (same-wave DS ops are
// pipeline-ordered in HW); no s_barrier -> waves drift freely.
__device__ inline void wave_fence() {
    asm volatile("" ::: "memory");
    __builtin_amdgcn_wave_barrier();
    __builtin_amdgcn_sched_barrier(0);
}

// ---------------- prep: cast + 3 weight transposes + bias concat, one launch ----------------
// block roles by blockIdx.x: [0,16384) cast feats; [16384,16640) W_theta^T;
// [16640,16896) W_phi^T; [16896,17920) W_gcn^T; [17920] bias concat.

__device__ void tcast_body(const float* __restrict__ in, unsigned short* __restrict__ out,
                           int K, int N, int bx, int by, float tile[32][33]) {
    const int t  = threadIdx.x;
    const int tx = t & 31, ty = t >> 5;
    const int k0 = by * 32, n0 = bx * 32;
#pragma unroll
    for (int r = 0; r < 4; ++r)
        tile[ty + r * 8][tx] = in[(long)(k0 + ty + r * 8) * N + n0 + tx];
    __syncthreads();
#pragma unroll
    for (int r = 0; r < 4; ++r)
        out[(long)(n0 + ty + r * 8) * K + k0 + tx] = f2bf(tile[tx][ty + r * 8]);
}

__global__ __launch_bounds__(256)
void prep(const float* __restrict__ feats, unsigned short* __restrict__ featsb,
          const float* __restrict__ W_theta, const float* __restrict__ W_phi,
          const float* __restrict__ W_gcn,
          unsigned short* __restrict__ Wtp, unsigned short* __restrict__ Wgt,
          const float* __restrict__ bt, const float* __restrict__ bp,
          float* __restrict__ bias512) {
    __shared__ float tile[32][33];
    const int bid = blockIdx.x;
    const int t   = threadIdx.x;
    if (bid < 16384) {
        long i = ((long)bid * 256 + t) * 8;
        if (i + 8 <= 33554432L) {
            f32x4 a = *(const f32x4*)(feats + i);
            f32x4 b = *(const f32x4*)(feats + i + 4);
            u16x8 o;
#pragma unroll
            for (int c = 0; c < 4; ++c) { o[c] = f2bf(a[c]); o[4 + c] = f2bf(b[c]); }
            *(u16x8*)(featsb + i) = o;
        }
    } else if (bid < 16640) {
        int r = bid - 16384;
        tcast_body(W_theta, Wtp, 1024, 256, r & 7, r >> 3, tile);
    } else if (bid < 16896) {
        int r = bid - 16640;
        tcast_body(W_phi, Wtp + 256 * 1024, 1024, 256, r & 7, r >> 3, tile);
    } else if (bid < 17920) {
        int r = bid - 16896;
        tcast_body(W_gcn, Wgt, 1024, 1024, r & 31, r >> 5, tile);
    } else {
        bias512[t]       = bt[t];
        bias512[t + 256] = bp[t];
    }
}

// ---------------- gemm_bt: C[M][N] = act(A[M][K] @ Bt[N][K]^T + bias) ----------------
// 128x128 tile, 4 waves 2x2, each wave 64x64 (4x4 mfma 16x16x32 acc), BK=64.
// Verified m97-class structure: 32 KB LDS -> 4 blocks/CU, inter-block overlap (m114)
// is what hides the per-tile vmcnt(0)+barrier drain.
// SWIZ: 1 = B-operand reused (mtile fastest, LOG_FAST=log2(gridDim.x));
//       2 = A-operand reused (ntile fastest, LOG_FAST=log2(gridDim.y)).

template<int RELU, int STORE_BF16, int SWIZ, int LOG_FAST>
__global__ __launch_bounds__(256, 4)
void gemm_bt(const unsigned short* __restrict__ A, const unsigned short* __restrict__ Bt,
             const float* __restrict__ bias, void* __restrict__ Cout,
             int M, int N, int K) {
    __shared__ __align__(16) unsigned short As[128 * 64];   // 16 KB
    __shared__ __align__(16) unsigned short Bs[128 * 64];   // 16 KB
    const int t    = threadIdx.x;
    const int lane = t & 63;
    const int w    = t >> 6;
    const int l15  = lane & 15;
    const int q    = lane >> 4;

    long mtile, ntile;
    if (SWIZ == 1) {
        long linear = (long)blockIdx.y * gridDim.x + blockIdx.x;  // dispatch order, x fastest
        int  xcd  = (int)(linear & 7);
        long slot = linear >> 3;
        mtile = slot & ((1 << LOG_FAST) - 1);
        ntile = (long)xcd * (gridDim.y >> 3) + (slot >> LOG_FAST);
    } else if (SWIZ == 2) {
        long linear = (long)blockIdx.y * gridDim.x + blockIdx.x;
        int  xcd  = (int)(linear & 7);
        long slot = linear >> 3;
        ntile = slot & ((1 << LOG_FAST) - 1);
        mtile = (long)xcd * (gridDim.x >> 3) + (slot >> LOG_FAST);
    } else {
        mtile = blockIdx.x; ntile = blockIdx.y;
    }
    const long tileM = mtile * 128;
    const long tileN = ntile * 128;
    const int wm = (w & 1) * 64;
    const int wn = (w >> 1) * 64;

    f32x4 acc[4][4] = {};

    // staging: 4 issues per operand. issue i, thread t -> LDS chunkid = i*256+t
    //   -> LDS row = i*32 + (t>>3), LDS slot = t&7.
    // lane fetches GLOBAL chunk (t&7)^(row&7) so slot s of row r holds chunk s^(r&7).
    const int rS = t >> 3;                 // 0..31
    const int cS = (t & 7) ^ (rS & 7);     // swizzled global chunk
    const unsigned short* gA = A  + (tileM + rS) * (long)K + cS * 8;
    const unsigned short* gB = Bt + (tileN + rS) * (long)K + cS * 8;

    for (int kt = 0; kt < K; kt += 64) {
        __syncthreads();                 // protect LDS reuse
#pragma unroll
        for (int i = 0; i < 4; ++i) {
            gld_lds16(gA + (long)i * 32 * K + kt, As + (i * 256 + w * 64) * 8);
            gld_lds16(gB + (long)i * 32 * K + kt, Bs + (i * 256 + w * 64) * 8);
        }
        __syncthreads();                 // drain staging (compiler emits vmcnt(0))
#pragma unroll
        for (int ks = 0; ks < 2; ++ks) {
            const int slot = (ks * 4 + q) ^ (l15 & 7);   // row&7 == l15&7 (16|wm,mi*16)
            bf16x8 af[4], bf[4];
#pragma unroll
            for (int mi = 0; mi < 4; ++mi)
                af[mi] = *(const bf16x8*)(As + (wm + mi * 16 + l15) * 64 + slot * 8);
#pragma unroll
            for (int ni = 0; ni < 4; ++ni)
                bf[ni] = *(const bf16x8*)(Bs + (wn + ni * 16 + l15) * 64 + slot * 8);
#pragma unroll
            for (int mi = 0; mi < 4; ++mi)
#pragma unroll
                for (int ni = 0; ni < 4; ++ni)
                    acc[mi][ni] = __builtin_amdgcn_mfma_f32_16x16x32_bf16(af[mi], bf[ni],
                                                                          acc[mi][ni], 0, 0, 0);
        }
    }

    // epilogue: C/D layout col=lane&15, row=(lane>>4)*4+reg (verified m89/m91)
#pragma unroll
    for (int mi = 0; mi < 4; ++mi) {
#pragma unroll
        for (int ni = 0; ni < 4; ++ni) {
            long row0 = tileM + wm + mi * 16 + q * 4;
            long col  = tileN + wn + ni * 16 + l15;
            float bv = bias ? bias[col] : 0.f;
#pragma unroll
            for (int r = 0; r < 4; ++r) {
                float v = acc[mi][ni][r] + bv;
                if (RELU) v = fmaxf(v, 0.f);
                long idx = (row0 + r) * N + col;
                if (STORE_BF16) ((unsigned short*)Cout)[idx] = f2bf(v);
                else            ((float*)Cout)[idx] = v;
            }
        }
    }
}

// ---------------- fused: sim -> mask -> softmax -> rg + out = relu(P @ H) ----------------
// ZERO-BARRIER wave-autonomous version. Block = (b, gh) g-split; wave w owns rows
// w*16..w*16+15 end-to-end: sim (MFMA rows), softmax (i=t>>2 lands in same wave),
// PV (A-frag = own P rows, sweeps all 512 g of the gh half). All LDS handoffs are
// intra-wave (HW-ordered DS pipe; wave_fence pins compiler). HtT B-frags are shared
// across the 4 waves -> redundant reads are L2 hits, HBM fetch unchanged.
// Rolling 6-deep register prefetch of HtT (12 loads in flight, static ring index).

__global__ __launch_bounds__(256, 4)
void fused_softmax_out(const unsigned short* __restrict__ thetaphi,  // [32768][512] bf16
                       const float* __restrict__ boxes,              // [512][64][4]
                       const unsigned short* __restrict__ HtT,       // [1024][32768] bf16
                       float* __restrict__ rg_out,                   // relation_graph f32
                       float* __restrict__ out) {                    // [512][64][1024] f32
    __shared__ __align__(16) float sim_s[64][68];
    __shared__ __align__(16) unsigned short Pb[64][72];   // 144B row stride: 16B-aligned
    const int t    = threadIdx.x;
    const int b    = blockIdx.x >> 1;
    const int gh   = blockIdx.x & 1;
    const int lane = t & 63;
    const int w    = t >> 6;
    const int l15  = lane & 15;
    const int q    = lane >> 4;

    // ---- rolling HtT prefetch: slots 0..5 issued before any compute ----
    const unsigned short* HtB = HtT + (long)b * 64;       // column offset
    bf16x8 hb0[6], hb1[6];
#pragma unroll
    for (int nt = 0; nt < 6; ++nt) {
        const int g0 = gh * 512 + nt * 16;
        const unsigned short* hp = HtB + (long)(g0 + l15) * 32768 + q * 8;
        hb0[nt] = *(const bf16x8*)(hp);        // j = q*8..q*8+7
        hb1[nt] = *(const bf16x8*)(hp + 32);   // j = 32+q*8..
    }
    __builtin_amdgcn_sched_barrier(0);         // pin prefetch issue before compute

    // box centers in registers: lane ln holds box ln (every wave loads all 64)
    float cx, cy;
    {
        float4 bx = *(const float4*)(boxes + ((long)b * 64 + lane) * 4);
        cx = (bx.x + bx.z) * 0.5f;
        cy = (bx.y + bx.w) * 0.5f;
    }

    // sim[i][j] = theta_i . phi_j / 16 ; wave w produces rows w*16..w*16+15
    {
        f32x4 acc[4] = {};
        const unsigned short* thA = thetaphi + ((long)b * 64 + w * 16 + l15) * 512 + q * 8;
        const unsigned short* thB = thetaphi + ((long)b * 64 + l15) * 512 + 256 + q * 8;
#pragma unroll
        for (int kt = 0; kt < 256; kt += 32) {
            bf16x8 a = *(const bf16x8*)(thA + kt);
#pragma unroll
            for (int ni = 0; ni < 4; ++ni) {
                bf16x8 bb = *(const bf16x8*)(thB + (long)ni * 16 * 512 + kt);
                acc[ni] = __builtin_amdgcn_mfma_f32_16x16x32_bf16(a, bb, acc[ni], 0, 0, 0);
            }
        }
#pragma unroll
        for (int ni = 0; ni < 4; ++ni)
#pragma unroll
            for (int r = 0; r < 4; ++r)
                sim_s[w * 16 + q * 4 + r][ni * 16 + l15] = acc[ni][r] * 0.0625f;
    }
    wave_fence();   // intra-wave sim_s handoff (rows w*16.. produced & consumed by wave w)

    // softmax row i = t>>2 (in wave w's row range), 4 lanes/row, 16 cols each
    {
        const int i  = t >> 2;
        const int j0 = (t & 3) * 16;
        const float cxi = __shfl(cx, i & 63, 64);
        const float cyi = __shfl(cy, i & 63, 64);
        const float thr = (float)(0.2 * 157.0);
        float vals[16];
        float mx = -__builtin_inff();
#pragma unroll
        for (int jj = 0; jj < 16; ++jj) {
            int j = j0 + jj;
            float dx = cxi - __shfl(cx, j, 64);
            float dy = cyi - __shfl(cy, j, 64);
            bool msk = sqrtf(dx * dx + dy * dy) > thr;
            float s = msk ? -__builtin_inff() : sim_s[i][j];
            vals[jj] = s;
            mx = fmaxf(mx, s);
        }
        mx = fmaxf(mx, __shfl_xor(mx, 1, 64));
        mx = fmaxf(mx, __shfl_xor(mx, 2, 64));
        float sum = 0.f;
#pragma unroll
        for (int jj = 0; jj < 16; ++jj) {
            float e = (vals[jj] == -__builtin_inff()) ? 0.f : __expf(vals[jj] - mx);
            vals[jj] = e;
            sum += e;
        }
        sum += __shfl_xor(sum, 1, 64);
        sum += __shfl_xor(sum, 2, 64);
        float inv = 1.f / sum;   // self always unmasked -> sum > 0
        f32x4 pv[4];
#pragma unroll
        for (int jj = 0; jj < 16; ++jj) {
            float p = vals[jj] * inv;
            pv[jj >> 2][jj & 3] = p;
            Pb[i][j0 + jj] = f2bf(p);
        }
        if (gh == 0) {
            float* rgR = rg_out + ((long)b * 64 + i) * 64 + j0;
#pragma unroll
            for (int c = 0; c < 4; ++c) *(f32x4*)(rgR + c * 4) = pv[c];
        }
    }
    wave_fence();   // intra-wave Pb handoff (rows w*16.. produced & consumed by wave w)

    // PV: out[i][g] = relu( sum_j P[i][j] * H[j][g] ); wave w: rows w*16..+15,
    // g sweeps the gh half (32 nt of 16 g). B-frags from the rolling prefetch ring.
    {
        bf16x8 af0 = *(const bf16x8*)(&Pb[w * 16 + l15][q * 8]);
        bf16x8 af1 = *(const bf16x8*)(&Pb[w * 16 + l15][32 + q * 8]);
        float* outR = out + (long)b * 65536 + (long)(w * 16 + q * 4) * 1024 + gh * 512 + l15;
#pragma unroll
        for (int nt = 0; nt < 32; ++nt) {
            const int s = nt % 6;
            f32x4 acc = {};
            acc = __builtin_amdgcn_mfma_f32_16x16x32_bf16(af0, hb0[s], acc, 0, 0, 0);
            acc = __builtin_amdgcn_mfma_f32_16x16x32_bf16(af1, hb1[s], acc, 0, 0, 0);
            if (nt + 6 < 32) {                    // refill consumed slot (static idx)
                const int g0 = gh * 512 + (nt + 6) * 16;
                const unsigned short* hp = HtB + (long)(g0 + l15) * 32768 + q * 8;
                hb0[s] = *(const bf16x8*)(hp);
                hb1[s] = *(const bf16x8*)(hp + 32);
            }
#pragma unroll
            for (int r = 0; r < 4; ++r)
                outR[(long)r * 1024 + nt * 16] = fmaxf(acc[r], 0.f);
        }
    }
}

// ---------------- launch ----------------

extern "C" void kernel_launch(void* const* d_in, const int* in_sizes, int n_in,
                              void* d_out, int out_size, void* d_ws, size_t ws_size,
                              hipStream_t stream) {
    const float* feats   = (const float*)d_in[0];
    const float* boxes   = (const float*)d_in[1];
    const float* W_theta = (const float*)d_in[2];
    const float* b_theta = (const float*)d_in[3];
    const float* W_phi   = (const float*)d_in[4];
    const float* b_phi   = (const float*)d_in[5];
    const float* W_gcn   = (const float*)d_in[6];
    float* out = (float*)d_out;

    // workspace layout (~171 MB)
    char* ws = (char*)d_ws;
    unsigned short* featsb   = (unsigned short*)(ws);                // 67108864 B
    unsigned short* thetaphi = (unsigned short*)(ws + 67108864);     // 33554432 B
    unsigned short* HtT      = (unsigned short*)(ws + 100663296);    // 67108864 B
    unsigned short* Wtp      = (unsigned short*)(ws + 167772160);    //  1048576 B
    unsigned short* Wgt      = (unsigned short*)(ws + 168820736);    //  2097152 B
    float*          bias512  = (float*)(ws + 170917888);             //     2048 B

    // cast + weight transposes + bias, one launch
    prep<<<17921, 256, 0, stream>>>(feats, featsb, W_theta, W_phi, W_gcn,
                                    Wtp, Wgt, b_theta, b_phi, bias512);

    // theta|phi: [32768][512] bf16 row-major. A=featsb reused by 4 ntiles -> SWIZ=2
    gemm_bt<0, 1, 2, 2><<<dim3(256, 4), 256, 0, stream>>>(featsb, Wtp, bias512, thetaphi,
                                                          MM, 512, 1024);
    // H^T = Wgcn^T @ feats^T : [1024][32768] bf16. B=featsb reused by 8 mtiles -> SWIZ=1
    gemm_bt<0, 1, 1, 3><<<dim3(8, 256), 256, 0, stream>>>(Wgt, featsb, nullptr, HtT,
                                                          1024, MM, 1024);
    // relation graph + out = relu(P @ H), g-split x2, zero-barrier wave-autonomous
    fused_softmax_out<<<BB * 2, 256, 0, stream>>>(thetaphi, boxes, HtT, out + RG_OFF, out);
}

// Round 5
// 415.906 us; speedup vs baseline: 1.1606x; 1.0010x over previous
//
#include <hip/hip_runtime.h>
#include <hip/hip_bf16.h>
#include <math.h>

// Shapes (fixed by the problem)
#define BB   512
#define NN   64
#define NFG  1024
#define NFR  256
#define MM   (BB * NN)          // 32768
#define RG_OFF 33554432L        // out elements before relation_graph

typedef __attribute__((ext_vector_type(8))) short bf16x8;   // 8 bf16 = 4 VGPRs (guide §3)
typedef __attribute__((ext_vector_type(4))) float f32x4;
typedef __attribute__((ext_vector_type(8))) unsigned short u16x8;

__device__ inline unsigned short f2bf(float f) {
    union { float f; unsigned u; } v; v.f = f;
    unsigned u = v.u;
    return (unsigned short)((u + 0x7FFFu + ((u >> 16) & 1u)) >> 16);  // RNE
}

__device__ inline void gld_lds16(const unsigned short* g, unsigned short* l) {
    // async global->LDS, 16B per lane; LDS dst is wave-uniform base + lane*16
    __builtin_amdgcn_global_load_lds((const __attribute__((address_space(1))) void*)g,
                                     (__attribute__((address_space(3))) void*)l, 16, 0, 0);
}

// intra-wave LDS handoff fence: pins compiler ordering (same-wave DS ops are
// pipeline-ordered in HW); no s_barrier -> waves drift freely.
__device__ inline void wave_fence() {
    asm volatile("" ::: "memory");
    __builtin_amdgcn_wave_barrier();
    __builtin_amdgcn_sched_barrier(0);
}

// ---------------- prep: cast + 3 weight transposes + bias concat, one launch ----------------

__device__ void tcast_body(const float* __restrict__ in, unsigned short* __restrict__ out,
                           int K, int N, int bx, int by, float tile[32][33]) {
    const int t  = threadIdx.x;
    const int tx = t & 31, ty = t >> 5;
    const int k0 = by * 32, n0 = bx * 32;
#pragma unroll
    for (int r = 0; r < 4; ++r)
        tile[ty + r * 8][tx] = in[(long)(k0 + ty + r * 8) * N + n0 + tx];
    __syncthreads();
#pragma unroll
    for (int r = 0; r < 4; ++r)
        out[(long)(n0 + ty + r * 8) * K + k0 + tx] = f2bf(tile[tx][ty + r * 8]);
}

__global__ __launch_bounds__(256)
void prep(const float* __restrict__ feats, unsigned short* __restrict__ featsb,
          const float* __restrict__ W_theta, const float* __restrict__ W_phi,
          const float* __restrict__ W_gcn,
          unsigned short* __restrict__ Wtp, unsigned short* __restrict__ Wgt,
          const float* __restrict__ bt, const float* __restrict__ bp,
          float* __restrict__ bias512) {
    __shared__ float tile[32][33];
    const int bid = blockIdx.x;
    const int t   = threadIdx.x;
    if (bid < 16384) {
        long i = ((long)bid * 256 + t) * 8;
        if (i + 8 <= 33554432L) {
            f32x4 a = *(const f32x4*)(feats + i);
            f32x4 b = *(const f32x4*)(feats + i + 4);
            u16x8 o;
#pragma unroll
            for (int c = 0; c < 4; ++c) { o[c] = f2bf(a[c]); o[4 + c] = f2bf(b[c]); }
            *(u16x8*)(featsb + i) = o;
        }
    } else if (bid < 16640) {
        int r = bid - 16384;
        tcast_body(W_theta, Wtp, 1024, 256, r & 7, r >> 3, tile);
    } else if (bid < 16896) {
        int r = bid - 16640;
        tcast_body(W_phi, Wtp + 256 * 1024, 1024, 256, r & 7, r >> 3, tile);
    } else if (bid < 17920) {
        int r = bid - 16896;
        tcast_body(W_gcn, Wgt, 1024, 1024, r & 31, r >> 5, tile);
    } else {
        bias512[t]       = bt[t];
        bias512[t + 256] = bp[t];
    }
}

// ---------------- gemm8p: 8-phase pipelined 256x256 GEMM (T3+T4+T5) ----------------
// C[M][N] = A[M][K] @ Bt[N][K]^T + bias, bf16 out. BK=64, 8 waves (2M x 4N),
// wave tile 128x64 (8x4 frags), LDS 2 dbuf x (256x64) per operand = 128 KB.
// Per K-tile j: 4 phases {ds_read frags; stage 1 half-tile of j+1; barrier;
// lgkmcnt(0); setprio(1); 16 MFMA; setprio(0); barrier}. Counted vmcnt only:
// entry vmcnt(2) (A0,B0,B1 of j landed; A1 in flight), mid vmcnt(4) (A1 landed).
// Stage targets dbuf[(j+1)&1], whose content (j-1) was fully consumed before
// j's entry barrier -> race-free. Stage order A0,B0,B1,A1 makes the ledger exact:
//   entry of j: outstanding {A0,B0,B1,A1}(j)=8 -> vmcnt(2) leaves A1(j)
//   mid of j:   outstanding {A1(j), A0(j+1), B0(j+1)}=6 -> vmcnt(4) leaves 4
// Wave decomposition: wm64=(w>>2)*64 selects 64 rows inside each 128-row half
// (mg selects the half), wn64=(w&3)*64. Swizzle: stage fetches global chunk
// (t&7)^((t>>3)&7); read slot (ks*4+q)^(l15&7) — verified, 0 bank conflicts (r1).

template<int FASTN, int LOGF>
__global__ __launch_bounds__(512, 2)
void gemm8p(const unsigned short* __restrict__ A, const unsigned short* __restrict__ Bt,
            const float* __restrict__ bias, unsigned short* __restrict__ Cout,
            int M, int N, int K) {
    __shared__ __align__(16) unsigned short As[2 * 256 * 64];   // 64 KB
    __shared__ __align__(16) unsigned short Bs[2 * 256 * 64];   // 64 KB
    const int t    = threadIdx.x;
    const int lane = t & 63;
    const int w    = t >> 6;
    const int l15  = lane & 15;
    const int q    = lane >> 4;
    const int wm64 = (w >> 2) * 64;   // within-half row offset
    const int wn64 = (w & 3) * 64;

    // bijective XCD swizzle (nwg % 8 == 0 for both call sites)
    long mtile, ntile;
    {
        long lin  = blockIdx.x;
        int  xcd  = (int)(lin & 7);
        long slot = lin >> 3;
        long fast = slot & ((1 << LOGF) - 1);
        long rest = slot >> LOGF;
        if (FASTN) { ntile = fast; mtile = (long)xcd * ((M >> 8) >> 3) + rest; }
        else       { mtile = fast; ntile = (long)xcd * ((N >> 8) >> 3) + rest; }
    }
    const long tileM = mtile * 256;
    const long tileN = ntile * 256;

    f32x4 acc[8][4] = {};
    bf16x8 bfr[2][4];   // B frags per k-step, persist across the two mg phases

    // staging geometry: one gload_lds = 512 thr x 16B = 64 rows of 128 B
    const int rT = t >> 3;                 // row within 64-row block
    const int cS = (t & 7) ^ (rT & 7);     // pre-swizzled global 16B chunk
    const unsigned short* gA = A  + (tileM + rT) * (long)K + cS * 8;
    const unsigned short* gB = Bt + (tileN + rT) * (long)K + cS * 8;
    const int NT = K >> 6;

    auto stageA = [&](int d, int hf, int j) {
#pragma unroll
        for (int i = 0; i < 2; ++i)
            gld_lds16(gA + (long)(hf * 128 + i * 64) * K + (long)j * 64,
                      As + d * 16384 + hf * 8192 + i * 4096 + w * 512);
    };
    auto stageB = [&](int d, int hf, int j) {
#pragma unroll
        for (int i = 0; i < 2; ++i)
            gld_lds16(gB + (long)(hf * 128 + i * 64) * K + (long)j * 64,
                      Bs + d * 16384 + hf * 8192 + i * 4096 + w * 512);
    };

#define PHASE(d, MG, KS, LOADB, STMT) do {                                            \
    const int slot_ = ((KS) * 4 + q) ^ (l15 & 7);                                     \
    const unsigned short* Ab_ = As + (d) * 16384;                                     \
    const unsigned short* Bb_ = Bs + (d) * 16384;                                     \
    bf16x8 af_[4];                                                                    \
    _Pragma("unroll")                                                                 \
    for (int ai = 0; ai < 4; ++ai)                                                    \
        af_[ai] = *(const bf16x8*)(Ab_ + ((MG) * 128 + wm64 + ai * 16 + l15) * 64 + slot_ * 8); \
    if (LOADB) {                                                                      \
        _Pragma("unroll")                                                             \
        for (int ni = 0; ni < 4; ++ni)                                                \
            bfr[KS][ni] = *(const bf16x8*)(Bb_ + (wn64 + ni * 16 + l15) * 64 + slot_ * 8);      \
    }                                                                                 \
    STMT;                                                                             \
    __builtin_amdgcn_s_barrier();                                                     \
    asm volatile("s_waitcnt lgkmcnt(0)" ::: "memory");                                \
    __builtin_amdgcn_sched_barrier(0);                                                \
    __builtin_amdgcn_s_setprio(1);                                                    \
    _Pragma("unroll")                                                                 \
    for (int ai = 0; ai < 4; ++ai) {                                                  \
        _Pragma("unroll")                                                             \
        for (int ni = 0; ni < 4; ++ni)                                                \
            acc[(MG) * 4 + ai][ni] = __builtin_amdgcn_mfma_f32_16x16x32_bf16(         \
                af_[ai], bfr[KS][ni], acc[(MG) * 4 + ai][ni], 0, 0, 0);               \
    }                                                                                 \
    __builtin_amdgcn_s_setprio(0);                                                    \
} while (0)

    // prologue: stage K-tile 0 in ledger order A0,B0,B1,A1 (8 loads in flight)
    stageA(0, 0, 0);
    stageB(0, 0, 0);
    stageB(0, 1, 0);
    stageA(0, 1, 0);

    for (int j = 0; j < NT; ++j) {
        const int d  = j & 1;
        const int st = (j + 1 < NT);
        // entry guard: A0(j),B0(j),B1(j) landed for every wave; A1(j) may fly
        asm volatile("s_waitcnt vmcnt(2)" ::: "memory");
        __builtin_amdgcn_s_barrier();
        __builtin_amdgcn_sched_barrier(0);
        PHASE(d, 0, 0, 1, { if (st) stageA(d ^ 1, 0, j + 1); });
        __builtin_amdgcn_s_barrier();
        PHASE(d, 0, 1, 1, { if (st) stageB(d ^ 1, 0, j + 1); });
        // mid guard: A1(j) landed (outstanding then: A0(j+1),B0(j+1) = 4)
        if (j == NT - 1) asm volatile("s_waitcnt vmcnt(0)" ::: "memory");
        else             asm volatile("s_waitcnt vmcnt(4)" ::: "memory");
        __builtin_amdgcn_s_barrier();
        __builtin_amdgcn_sched_barrier(0);
        PHASE(d, 1, 0, 0, { if (st) stageB(d ^ 1, 1, j + 1); });
        __builtin_amdgcn_s_barrier();
        PHASE(d, 1, 1, 0, { if (st) stageA(d ^ 1, 1, j + 1); });
        // p3's post-barrier is the next iteration's entry barrier
    }
#undef PHASE

    // epilogue: C/D layout col=lane&15, row=(lane>>4)*4+reg (verified m89/m91)
#pragma unroll
    for (int a = 0; a < 8; ++a) {
        long row0 = tileM + (a >> 2) * 128 + wm64 + (a & 3) * 16 + q * 4;
#pragma unroll
        for (int ni = 0; ni < 4; ++ni) {
            long col = tileN + wn64 + ni * 16 + l15;
            float bv = bias ? bias[col] : 0.f;
#pragma unroll
            for (int r = 0; r < 4; ++r) {
                float v = acc[a][ni][r] + bv;
                Cout[(row0 + r) * N + col] = f2bf(v);
            }
        }
    }
}

// ---------------- fused: sim -> mask -> softmax -> rg + out = relu(P @ H) ----------------
// ZERO-BARRIER wave-autonomous version (round 4, neutral but simpler). Block =
// (b, gh) g-split; wave w owns rows w*16..+15 end-to-end. Rolling 6-deep HtT
// register prefetch.

__global__ __launch_bounds__(256, 4)
void fused_softmax_out(const unsigned short* __restrict__ thetaphi,  // [32768][512] bf16
                       const float* __restrict__ boxes,              // [512][64][4]
                       const unsigned short* __restrict__ HtT,       // [1024][32768] bf16
                       float* __restrict__ rg_out,                   // relation_graph f32
                       float* __restrict__ out) {                    // [512][64][1024] f32
    __shared__ __align__(16) float sim_s[64][68];
    __shared__ __align__(16) unsigned short Pb[64][72];   // 144B row stride: 16B-aligned
    const int t    = threadIdx.x;
    const int b    = blockIdx.x >> 1;
    const int gh   = blockIdx.x & 1;
    const int lane = t & 63;
    const int w    = t >> 6;
    const int l15  = lane & 15;
    const int q    = lane >> 4;

    // ---- rolling HtT prefetch: slots 0..5 issued before any compute ----
    const unsigned short* HtB = HtT + (long)b * 64;       // column offset
    bf16x8 hb0[6], hb1[6];
#pragma unroll
    for (int nt = 0; nt < 6; ++nt) {
        const int g0 = gh * 512 + nt * 16;
        const unsigned short* hp = HtB + (long)(g0 + l15) * 32768 + q * 8;
        hb0[nt] = *(const bf16x8*)(hp);        // j = q*8..q*8+7
        hb1[nt] = *(const bf16x8*)(hp + 32);   // j = 32+q*8..
    }
    __builtin_amdgcn_sched_barrier(0);         // pin prefetch issue before compute

    // box centers in registers: lane ln holds box ln (every wave loads all 64)
    float cx, cy;
    {
        float4 bx = *(const float4*)(boxes + ((long)b * 64 + lane) * 4);
        cx = (bx.x + bx.z) * 0.5f;
        cy = (bx.y + bx.w) * 0.5f;
    }

    // sim[i][j] = theta_i . phi_j / 16 ; wave w produces rows w*16..w*16+15
    {
        f32x4 acc[4] = {};
        const unsigned short* thA = thetaphi + ((long)b * 64 + w * 16 + l15) * 512 + q * 8;
        const unsigned short* thB = thetaphi + ((long)b * 64 + l15) * 512 + 256 + q * 8;
#pragma unroll
        for (int kt = 0; kt < 256; kt += 32) {
            bf16x8 a = *(const bf16x8*)(thA + kt);
#pragma unroll
            for (int ni = 0; ni < 4; ++ni) {
                bf16x8 bb = *(const bf16x8*)(thB + (long)ni * 16 * 512 + kt);
                acc[ni] = __builtin_amdgcn_mfma_f32_16x16x32_bf16(a, bb, acc[ni], 0, 0, 0);
            }
        }
#pragma unroll
        for (int ni = 0; ni < 4; ++ni)
#pragma unroll
            for (int r = 0; r < 4; ++r)
                sim_s[w * 16 + q * 4 + r][ni * 16 + l15] = acc[ni][r] * 0.0625f;
    }
    wave_fence();   // intra-wave sim_s handoff

    // softmax row i = t>>2 (in wave w's row range), 4 lanes/row, 16 cols each
    {
        const int i  = t >> 2;
        const int j0 = (t & 3) * 16;
        const float cxi = __shfl(cx, i & 63, 64);
        const float cyi = __shfl(cy, i & 63, 64);
        const float thr = (float)(0.2 * 157.0);
        float vals[16];
        float mx = -__builtin_inff();
#pragma unroll
        for (int jj = 0; jj < 16; ++jj) {
            int j = j0 + jj;
            float dx = cxi - __shfl(cx, j, 64);
            float dy = cyi - __shfl(cy, j, 64);
            bool msk = sqrtf(dx * dx + dy * dy) > thr;
            float s = msk ? -__builtin_inff() : sim_s[i][j];
            vals[jj] = s;
            mx = fmaxf(mx, s);
        }
        mx = fmaxf(mx, __shfl_xor(mx, 1, 64));
        mx = fmaxf(mx, __shfl_xor(mx, 2, 64));
        float sum = 0.f;
#pragma unroll
        for (int jj = 0; jj < 16; ++jj) {
            float e = (vals[jj] == -__builtin_inff()) ? 0.f : __expf(vals[jj] - mx);
            vals[jj] = e;
            sum += e;
        }
        sum += __shfl_xor(sum, 1, 64);
        sum += __shfl_xor(sum, 2, 64);
        float inv = 1.f / sum;   // self always unmasked -> sum > 0
        f32x4 pv[4];
#pragma unroll
        for (int jj = 0; jj < 16; ++jj) {
            float p = vals[jj] * inv;
            pv[jj >> 2][jj & 3] = p;
            Pb[i][j0 + jj] = f2bf(p);
        }
        if (gh == 0) {
            float* rgR = rg_out + ((long)b * 64 + i) * 64 + j0;
#pragma unroll
            for (int c = 0; c < 4; ++c) *(f32x4*)(rgR + c * 4) = pv[c];
        }
    }
    wave_fence();   // intra-wave Pb handoff

    // PV: out[i][g] = relu( sum_j P[i][j] * H[j][g] ); wave w: rows w*16..+15,
    // g sweeps the gh half (32 nt of 16 g). B-frags from the rolling prefetch ring.
    {
        bf16x8 af0 = *(const bf16x8*)(&Pb[w * 16 + l15][q * 8]);
        bf16x8 af1 = *(const bf16x8*)(&Pb[w * 16 + l15][32 + q * 8]);
        float* outR = out + (long)b * 65536 + (long)(w * 16 + q * 4) * 1024 + gh * 512 + l15;
#pragma unroll
        for (int nt = 0; nt < 32; ++nt) {
            const int s = nt % 6;
            f32x4 acc = {};
            acc = __builtin_amdgcn_mfma_f32_16x16x32_bf16(af0, hb0[s], acc, 0, 0, 0);
            acc = __builtin_amdgcn_mfma_f32_16x16x32_bf16(af1, hb1[s], acc, 0, 0, 0);
            if (nt + 6 < 32) {                    // refill consumed slot (static idx)
                const int g0 = gh * 512 + (nt + 6) * 16;
                const unsigned short* hp = HtB + (long)(g0 + l15) * 32768 + q * 8;
                hb0[s] = *(const bf16x8*)(hp);
                hb1[s] = *(const bf16x8*)(hp + 32);
            }
#pragma unroll
            for (int r = 0; r < 4; ++r)
                outR[(long)r * 1024 + nt * 16] = fmaxf(acc[r], 0.f);
        }
    }
}

// ---------------- launch ----------------

extern "C" void kernel_launch(void* const* d_in, const int* in_sizes, int n_in,
                              void* d_out, int out_size, void* d_ws, size_t ws_size,
                              hipStream_t stream) {
    const float* feats   = (const float*)d_in[0];
    const float* boxes   = (const float*)d_in[1];
    const float* W_theta = (const float*)d_in[2];
    const float* b_theta = (const float*)d_in[3];
    const float* W_phi   = (const float*)d_in[4];
    const float* b_phi   = (const float*)d_in[5];
    const float* W_gcn   = (const float*)d_in[6];
    float* out = (float*)d_out;

    // workspace layout (~171 MB)
    char* ws = (char*)d_ws;
    unsigned short* featsb   = (unsigned short*)(ws);                // 67108864 B
    unsigned short* thetaphi = (unsigned short*)(ws + 67108864);     // 33554432 B
    unsigned short* HtT      = (unsigned short*)(ws + 100663296);    // 67108864 B
    unsigned short* Wtp      = (unsigned short*)(ws + 167772160);    //  1048576 B
    unsigned short* Wgt      = (unsigned short*)(ws + 168820736);    //  2097152 B
    float*          bias512  = (float*)(ws + 170917888);             //     2048 B

    // cast + weight transposes + bias, one launch
    prep<<<17921, 256, 0, stream>>>(feats, featsb, W_theta, W_phi, W_gcn,
                                    Wtp, Wgt, b_theta, b_phi, bias512);

    // theta|phi: [32768][512] bf16. A=featsb shared by 2 ntiles -> ntile fastest.
    // grid 128x2 = 256 blocks (1/CU), 512 thr.
    gemm8p<1, 1><<<256, 512, 0, stream>>>(featsb, Wtp, bias512, thetaphi,
                                          MM, 512, 1024);
    // H^T = Wgcn^T @ feats^T : [1024][32768] bf16. B=featsb shared by 4 mtiles
    // -> mtile fastest. grid 4x128 = 512 blocks, 512 thr.
    gemm8p<0, 2><<<512, 512, 0, stream>>>(Wgt, featsb, nullptr, HtT,
                                          1024, MM, 1024);
    // relation graph + out = relu(P @ H), g-split x2, zero-barrier wave-autonomous
    fused_softmax_out<<<BB * 2, 256, 0, stream>>>(thetaphi, boxes, HtT, out + RG_OFF, out);
}